// Round 21
// baseline (277.116 us; speedup 1.0000x reference)
//
#include <hip/hip_runtime.h>
#include <hip/hip_bf16.h>
#include <stdint.h>

#define DEVI __device__ __forceinline__

typedef short s16x8 __attribute__((ext_vector_type(8)));
typedef short s16x4 __attribute__((ext_vector_type(4)));
typedef float f32x4 __attribute__((ext_vector_type(4)));

static constexpr int BB = 32, SS = 1000, EE = 1024, AA = 512;
static constexpr int MM = BB * SS;  // 32000

// workspace layout (bytes)
static constexpr size_t OFF_X16 = 0;                                   // [M][E] bf16 (dead after proj -> attn partials)
static constexpr size_t OFF_Q   = OFF_X16 + (size_t)MM * EE * 2;       // [M][A] bf16 (pre-scaled by log2e/sqrt(S))
static constexpr size_t OFF_K   = OFF_Q  + (size_t)MM * AA * 2;        // [M][A] bf16
static constexpr size_t OFF_VT  = OFF_K  + (size_t)MM * AA * 2;        // [B][A][S] bf16
static constexpr size_t OFF_WT  = OFF_VT + (size_t)BB * AA * SS * 2;   // 3 x [A][E] bf16

// attn K-split partials (inside X16 region)
static constexpr int PROWS = BB * 3 * 128;                 // 12288 rows per slot
static constexpr size_t ML_OFF = (size_t)2 * PROWS * 512;  // floats

DEVI unsigned short f2bf(float f) {
  union { float f; unsigned int u; } c; c.f = f;
  unsigned int u = c.u + 0x7fffu + ((c.u >> 16) & 1u);
  return (unsigned short)(u >> 16);
}

DEVI void gl_lds16(const void* g, void* l) {
  __builtin_amdgcn_global_load_lds(
      (const __attribute__((address_space(1))) unsigned int*)g,
      (__attribute__((address_space(3))) unsigned int*)l, 16, 0, 0);
}

DEVI void wg_barrier() {
  asm volatile("" ::: "memory");
  __builtin_amdgcn_s_barrier();
  asm volatile("" ::: "memory");
}

DEVI float fast_exp2(float x) {
#if __has_builtin(__builtin_amdgcn_exp2f)
  return __builtin_amdgcn_exp2f(x);
#else
  return __builtin_exp2f(x);
#endif
}

// ---------------------------------------------------------------- prep kernels
__global__ __launch_bounds__(256) void x_to_bf16_kernel(const float* __restrict__ x,
                                                        unsigned short* __restrict__ x16) {
  const long n4 = (long)MM * EE / 4;
  long i = (long)blockIdx.x * blockDim.x + threadIdx.x;
  const long stride = (long)gridDim.x * blockDim.x;
  for (; i < n4; i += stride) {
    const float4 v = ((const float4*)x)[i];
    ushort4 o;
    o.x = f2bf(v.x); o.y = f2bf(v.y); o.z = f2bf(v.z); o.w = f2bf(v.w);
    ((ushort4*)x16)[i] = o;
  }
}

__global__ __launch_bounds__(256) void wt_kernel(const float* __restrict__ Wq,
                                                 const float* __restrict__ Wk,
                                                 const float* __restrict__ Wv,
                                                 unsigned short* __restrict__ WT) {
  const float* W = (blockIdx.z == 0) ? Wq : (blockIdx.z == 1) ? Wk : Wv;
  unsigned short* out = WT + (size_t)blockIdx.z * AA * EE;
  __shared__ unsigned short t[64][65];
  const int k0 = blockIdx.x * 64, n0 = blockIdx.y * 64;
  #pragma unroll
  for (int i = 0; i < 16; ++i) {
    int idx = i * 256 + threadIdx.x;
    int r = idx >> 6, c = idx & 63;
    t[r][c] = f2bf(W[(size_t)(k0 + r) * AA + n0 + c]);
  }
  __syncthreads();
  #pragma unroll
  for (int i = 0; i < 16; ++i) {
    int idx = i * 256 + threadIdx.x;
    int r = idx >> 6, c = idx & 63;
    out[(size_t)(n0 + r) * EE + k0 + c] = t[c][r];
  }
}

// ---------------------------------------------------------------- QKV projection
// 256x256 tile, BK=64, 8 waves (2M x 4N). 4 FAT phases per K-tile-pair:
// phase = one QA-half: [QA==0: read all 16 B-frags (kept in regs across the
// group)] + 8 A-frags + stage 2 halves of next tile -> other buf -> barrier ->
// setprio(1) -> 64 MFMA -> setprio(0) -> [vmcnt(0) at group close] -> barrier.
// Same sync topology as the verified 8-phase (stages target the non-read buf;
// drain+barrier before the staged buf is read); fewer/fatter phases put the
// MFMA pipe ahead of LDS-issue. Last-staged halves get a full 64-MFMA phase of
// lead before the drain. Grid 750 1D, XCD-panel-pinned (groups of 48).
#define PROJ_PHASE4(BUF, QA, SKT, SWHa, SWHb, SBUF, DOVM)                      \
  {                                                                            \
    if ((QA) == 0) {                                                           \
      _Pragma("unroll") for (int kk = 0; kk < 2; ++kk) {                       \
        _Pragma("unroll") for (int g2 = 0; g2 < 4; ++g2) {                     \
          int row = wn * 64 + g2 * 16 + (lane & 15);                           \
          int cb = (kk * 64 + (lane >> 4) * 16) ^ ((row & 7) << 4);            \
          bR[kk][g2] = *(const s16x8*)(lds + 65536 + (BUF) * 32768 + row * 128 + cb); \
        }                                                                      \
      }                                                                        \
    }                                                                          \
    _Pragma("unroll") for (int kk = 0; kk < 2; ++kk) {                         \
      _Pragma("unroll") for (int f = 0; f < 4; ++f) {                          \
        int row = wm * 128 + ((QA) * 4 + f) * 16 + (lane & 15);                \
        int cb = (kk * 64 + (lane >> 4) * 16) ^ ((row & 7) << 4);              \
        aR[kk][f] = *(const s16x8*)(lds + (BUF) * 32768 + row * 128 + cb);     \
      }                                                                        \
    }                                                                          \
    if ((SKT) >= 0) { stage_half(SBUF, SKT, SWHa); stage_half(SBUF, SKT, SWHb); } \
    wg_barrier();                                                              \
    __builtin_amdgcn_s_setprio(1);                                             \
    _Pragma("unroll") for (int kk = 0; kk < 2; ++kk) {                         \
      _Pragma("unroll") for (int f = 0; f < 4; ++f) {                          \
        _Pragma("unroll") for (int g2 = 0; g2 < 4; ++g2) {                     \
          acc[(QA) * 4 + f][g2] = __builtin_amdgcn_mfma_f32_16x16x32_bf16(     \
              aR[kk][f], bR[kk][g2], acc[(QA) * 4 + f][g2], 0, 0, 0);          \
        }                                                                      \
      }                                                                        \
    }                                                                          \
    __builtin_amdgcn_s_setprio(0);                                             \
    if (DOVM) asm volatile("s_waitcnt vmcnt(0)" ::: "memory");                 \
    wg_barrier();                                                              \
  }

__global__ __launch_bounds__(512, 2) void proj_kernel(
    const unsigned short* __restrict__ X16, const unsigned short* __restrict__ WT,
    const float* __restrict__ bq, const float* __restrict__ bk, const float* __restrict__ bv,
    unsigned short* __restrict__ Qo, unsigned short* __restrict__ Ko,
    unsigned short* __restrict__ VTo) {
  __shared__ unsigned char lds[131072];  // A: [2 buf][256 rows][128B] @0 | B @65536
  const int tid = threadIdx.x, lane = tid & 63, wave = tid >> 6;
  const int wm = wave >> 2, wn = wave & 3;

  const int phys = blockIdx.x;
  int p, r;
  if (phys < 720) { int g = phys / 48, w = phys % 48; p = g * 8 + (w & 7); r = w >> 3; }
  else            { int w = phys - 720; p = 120 + w % 5; r = w / 5; }
  const int z = r >> 1, nidx = r & 1;
  const int m0 = p * 256, n0 = nidx * 256;
  const unsigned short* Wz = WT + (size_t)z * AA * EE;

  f32x4 acc[8][4];
  #pragma unroll
  for (int i = 0; i < 8; ++i)
    #pragma unroll
    for (int j = 0; j < 4; ++j) acc[i][j] = f32x4{0.f, 0.f, 0.f, 0.f};

  // hoisted per-thread stage chunk constants (2 chunks per half)
  unsigned int offH[2];
  #pragma unroll
  for (int i = 0; i < 2; ++i) {
    int c = i * 512 + tid;                 // 0..1023
    int rl = c >> 3, s = c & 7;
    int cb = (s * 16) ^ ((rl & 7) << 4);   // pre-swizzled source column (bytes)
    offH[i] = (unsigned)(rl * EE + (cb >> 1));
  }
  // stage one half-tile: which 0:A-h0 1:A-h1 2:B-h0 3:B-h1
  auto stage_half = [&](int buf, int kt, int which) {
    const int h = which & 1;
    const int isB = which >> 1;
    const unsigned short* srcb = isB ? (Wz + (size_t)(n0 + h * 128) * EE + kt * 64)
                                     : (X16 + (size_t)(m0 + h * 128) * EE + kt * 64);
    unsigned char* dstb = lds + (isB ? 65536 : 0) + buf * 32768 + h * 16384;
    #pragma unroll
    for (int i = 0; i < 2; ++i)
      gl_lds16(srcb + offH[i], dstb + (i * 512 + tid) * 16);
  };

  // prologue: tile 0 -> buf0 (4 halves)
  stage_half(0, 0, 0); stage_half(0, 0, 1); stage_half(0, 0, 2); stage_half(0, 0, 3);
  asm volatile("s_waitcnt vmcnt(0)" ::: "memory");
  wg_barrier();

  s16x8 aR[2][4];
  s16x8 bR[2][4];
  for (int J = 0; J < 8; ++J) {
    const int t1 = 2 * J + 1;
    const int t2 = (J < 7) ? (2 * J + 2) : -1;
    // Group A: tile 2J (buf0); stage tile t1 halves -> buf1
    PROJ_PHASE4(0, 0, t1, 0, 1, 1, false)
    PROJ_PHASE4(0, 1, t1, 2, 3, 1, true)
    // Group B: tile 2J+1 (buf1); stage tile t2 halves -> buf0
    PROJ_PHASE4(1, 0, t2, 0, 1, 0, false)
    PROJ_PHASE4(1, 1, t2, 2, 3, 0, true)
  }

  // ---- epilogue: bias (+scale for Q), bf16, LDS-coalesced in two passes ----
  const float* bias = (z == 0) ? bq : (z == 1) ? bk : bv;
  const float scale = (z == 0) ? 0.04562280215f : 1.0f;
  unsigned short* T = (unsigned short*)lds;   // [128][264] halfwords = 67.6KB
  float bv4[4];
  #pragma unroll
  for (int nf = 0; nf < 4; ++nf) bv4[nf] = bias[n0 + wn * 64 + nf * 16 + (lane & 15)];

  if (z != 2) {
    unsigned short* O = (z == 0) ? Qo : Ko;
    #pragma unroll
    for (int h = 0; h < 2; ++h) {
      if (wm == h) {
        #pragma unroll
        for (int mf = 0; mf < 8; ++mf)
          #pragma unroll
          for (int nf = 0; nf < 4; ++nf) {
            const int col = wn * 64 + nf * 16 + (lane & 15);
            #pragma unroll
            for (int j = 0; j < 4; ++j) {
              const int rr = mf * 16 + (lane >> 4) * 4 + j;
              T[rr * 264 + col] = f2bf((acc[mf][nf][j] + bv4[nf]) * scale);
            }
          }
      }
      wg_barrier();
      #pragma unroll
      for (int i = 0; i < 8; ++i) {
        int c2 = i * 512 + tid;                  // 4096 chunks of 16B
        int rr = c2 >> 5, ch = (c2 & 31) * 8;
        s16x8 chunk = *(const s16x8*)&T[rr * 264 + ch];
        *(s16x8*)&O[(size_t)(m0 + h * 128 + rr) * AA + n0 + ch] = chunk;
      }
      wg_barrier();
    }
  } else {
    #pragma unroll
    for (int h = 0; h < 2; ++h) {
      if ((wn >> 1) == h) {
        #pragma unroll
        for (int mf = 0; mf < 8; ++mf)
          #pragma unroll
          for (int nf = 0; nf < 4; ++nf) {
            const int al = (wn & 1) * 64 + nf * 16 + (lane & 15);   // a_local 0..127
            #pragma unroll
            for (int j = 0; j < 4; ++j) {
              const int sl = wm * 128 + mf * 16 + (lane >> 4) * 4 + j;  // s_local 0..255
              T[al * 264 + sl] = f2bf(acc[mf][nf][j] + bv4[nf]);
            }
          }
      }
      wg_barrier();
      #pragma unroll
      for (int i = 0; i < 8; ++i) {
        int c2 = i * 512 + tid;
        int rr = c2 >> 5, ch = (c2 & 31) * 8;    // rr: a_local, ch: s_local start
        s16x8 chunk = *(const s16x8*)&T[rr * 264 + ch];
        const int rowg0 = m0 + ch;               // 16B never straddles batch (8|1000)
        const int bb2 = rowg0 / SS, ss2 = rowg0 - bb2 * SS;
        *(s16x8*)&VTo[(size_t)bb2 * AA * SS + (size_t)(n0 + h * 128 + rr) * SS + ss2] = chunk;
      }
      wg_barrier();
    }
  }
}

// ---------------------------------------------------------------- fused causal attention
// (unchanged: K-split T=20, XCD pin, K+V dbuf, prefetch-before-compute)
__global__ __launch_bounds__(512, 2) void attn_kernel(
    const unsigned short* __restrict__ Qs, const unsigned short* __restrict__ Ks,
    const unsigned short* __restrict__ VT, float* __restrict__ out,
    float* __restrict__ part) {
  constexpr int KVB = 32;
  __shared__ unsigned char ldsK[2][KVB * AA * 2];
  __shared__ unsigned char ldsV[2][AA * KVB * 2];
  __shared__ unsigned char ldsP[8][16 * 80];

  const int tid = threadIdx.x, lane = tid & 63, wave = tid >> 6;
  const int L = blockIdx.x;
  const int b = L & 31;
  const int g = 7 - (L >> 5);

  const unsigned short* kbase = Ks + (size_t)b * SS * AA;
  const unsigned short* vbase = VT + (size_t)b * AA * SS;
  unsigned int koff[4], voff[4];
  #pragma unroll
  for (int i = 0; i < 4; ++i) {
    int c = i * 512 + tid;
    int r = c >> 6;
    int cb = ((c & 63) * 16) ^ ((r & 7) << 4);
    koff[i] = r * AA + (cb >> 1);
    int pair = c >> 3;
    int within = (c & 7) * 16;
    int half = within >> 6;
    int kb = (within & 63) ^ ((pair & 3) << 4);
    int a_ = pair * 2 + half;
    voff[i] = a_ * SS + (kb >> 1);
  }

  auto stageKV = [&](int buf, int t) {
    #pragma unroll
    for (int i = 0; i < 4; ++i)
      gl_lds16(kbase + koff[i] + (unsigned)(t * (KVB * AA)),
               &ldsK[buf][(i * 512 + tid) * 16]);
    #pragma unroll
    for (int i = 0; i < 4; ++i)
      gl_lds16(vbase + voff[i] + (unsigned)(t * KVB),
               &ldsV[buf][(i * 512 + tid) * 16]);
  };

  int ownN = 4 * (g + 1);
  int rb_[2], t0_[2], t1_[2], md_[2], cx_[2];
  int nph = 1;
  rb_[0] = 128 * g; t0_[0] = 0; t1_[0] = (ownN < 20) ? ownN : 20;
  md_[0] = (g <= 4) ? 0 : 1; cx_[0] = g - 5;
  if (g <= 2) {
    int r = 7 - g;
    rb_[1] = 128 * r; t0_[1] = 20; t1_[1] = 4 * (r + 1); md_[1] = 2; cx_[1] = r - 5;
    nph = 2;
  }

  for (int ph = 0; ph < nph; ++ph) {
    const int rowbase = rb_[ph], tbeg = t0_[ph], tend = t1_[ph];
    const int mode = md_[ph], cidx = cx_[ph];
    const int q0w = rowbase + wave * 16;

    s16x8 qf[16];
    {
      int qrow = q0w + (lane & 15);
      int qr = qrow < SS ? qrow : SS - 1;
      const unsigned short* qp = Qs + (size_t)(b * SS + qr) * AA + (lane >> 4) * 8;
      #pragma unroll
      for (int f = 0; f < 16; ++f) qf[f] = *(const s16x8*)(qp + f * 32);
    }

    f32x4 o[32];
    #pragma unroll
    for (int n = 0; n < 32; ++n) o[n] = f32x4{0.f, 0.f, 0.f, 0.f};
    float mrun[4], ps[4];
    #pragma unroll
    for (int j = 0; j < 4; ++j) { mrun[j] = -__builtin_inff(); ps[j] = 0.f; }

    stageKV(0, tbeg);
    asm volatile("s_waitcnt vmcnt(0)" ::: "memory");
    wg_barrier();

    for (int t = tbeg; t < tend; ++t) {
      const int cur = (t - tbeg) & 1;
      const int k0 = t * KVB;
      if (t + 1 < tend) stageKV(cur ^ 1, t + 1);

      f32x4 p0a = {0.f, 0.f, 0.f, 0.f}, p0b = {0.f, 0.f, 0.f, 0.f};
      f32x4 p1a = {0.f, 0.f, 0.f, 0.f}, p1b = {0.f, 0.f, 0.f, 0.f};
      {
        const int r0 = lane & 15;
        const int sw = (r0 & 7) << 4;
        const int kb16 = (lane >> 4) * 16;
        const int rb0 = r0 << 10, rb1 = (r0 + 16) << 10;
        #pragma unroll
        for (int f = 0; f < 8; ++f) {
          const int offA = f * 64 + kb16;
          const int offB = (f + 8) * 64 + kb16;
          s16x8 k0A = *(const s16x8*)&ldsK[cur][rb0 + (offA ^ sw)];
          s16x8 k1A = *(const s16x8*)&ldsK[cur][rb1 + (offA ^ sw)];
          s16x8 k0B = *(const s16x8*)&ldsK[cur][rb0 + (offB ^ sw)];
          s16x8 k1B = *(const s16x8*)&ldsK[cur][rb1 + (offB ^ sw)];
          p0a = __builtin_amdgcn_mfma_f32_16x16x32_bf16(qf[f], k0A, p0a, 0, 0, 0);
          p1a = __builtin_amdgcn_mfma_f32_16x16x32_bf16(qf[f], k1A, p1a, 0, 0, 0);
          p0b = __builtin_amdgcn_mfma_f32_16x16x32_bf16(qf[f + 8], k0B, p0b, 0, 0, 0);
          p1b = __builtin_amdgcn_mfma_f32_16x16x32_bf16(qf[f + 8], k1B, p1b, 0, 0, 0);
        }
      }
      f32x4 p0 = p0a + p0b, p1 = p1a + p1b;

      const int kcol = k0 + (lane & 15);
      float lm[4];
      #pragma unroll
      for (int j = 0; j < 4; ++j) {
        const int q = q0w + (lane >> 4) * 4 + j;
        float s0 = p0[j], s1 = p1[j];
        if (kcol > q || kcol >= SS) s0 = -__builtin_inff();
        if (kcol + 16 > q || kcol + 16 >= SS) s1 = -__builtin_inff();
        p0[j] = s0; p1[j] = s1;
        lm[j] = fmaxf(s0, s1);
      }
      const int myneed = (lm[0] > mrun[0] + 8.f) | (lm[1] > mrun[1] + 8.f) |
                         (lm[2] > mrun[2] + 8.f) | (lm[3] > mrun[3] + 8.f);
      if (__any(myneed)) {
        float rm[4] = {lm[0], lm[1], lm[2], lm[3]};
        #pragma unroll
        for (int st = 1; st <= 8; st <<= 1)
          #pragma unroll
          for (int j = 0; j < 4; ++j) rm[j] = fmaxf(rm[j], __shfl_xor(rm[j], st));
        float corr[4];
        #pragma unroll
        for (int j = 0; j < 4; ++j) {
          const float mnew = fmaxf(mrun[j], rm[j]);
          corr[j] = fast_exp2(mrun[j] - mnew);
          mrun[j] = mnew;
          ps[j] *= corr[j];
        }
        #pragma unroll
        for (int n = 0; n < 32; ++n)
          #pragma unroll
          for (int j = 0; j < 4; ++j) o[n][j] *= corr[j];
      }
      #pragma unroll
      for (int j = 0; j < 4; ++j) {
        const float e0 = fast_exp2(p0[j] - mrun[j]);
        const float e1 = fast_exp2(p1[j] - mrun[j]);
        ps[j] += e0 + e1;
        p0[j] = e0; p1[j] = e1;
      }

      {
        unsigned short* pb = (unsigned short*)&ldsP[wave][0];
        const int prow = (lane >> 4) * 4, pc = lane & 15;
        #pragma unroll
        for (int j = 0; j < 4; ++j) {
          pb[(prow + j) * 40 + pc]      = f2bf(p0[j]);
          pb[(prow + j) * 40 + pc + 16] = f2bf(p1[j]);
        }
      }
      s16x8 pa;
      {
        const unsigned char* pp = &ldsP[wave][(lane & 15) * 80 + (lane >> 4) * 16];
        s16x4 lo = *(const s16x4*)pp;
        s16x4 hi = *(const s16x4*)(pp + 8);
        pa = s16x8{lo[0], lo[1], lo[2], lo[3], hi[0], hi[1], hi[2], hi[3]};
      }

      #pragma unroll
      for (int n = 0; n < 32; ++n) {
        const int a_ = n * 16 + (lane & 15);
        const int pair = a_ >> 1;
        const int off = pair * 128 + (a_ & 1) * 64 + (((lane >> 4) * 16) ^ ((pair & 3) << 4));
        s16x8 vb = *(const s16x8*)&ldsV[cur][off];
        o[n] = __builtin_amdgcn_mfma_f32_16x16x32_bf16(pa, vb, o[n], 0, 0, 0);
      }

      asm volatile("s_waitcnt vmcnt(0)" ::: "memory");
      wg_barrier();
    }

    #pragma unroll
    for (int st = 1; st <= 8; st <<= 1)
      #pragma unroll
      for (int j = 0; j < 4; ++j) ps[j] += __shfl_xor(ps[j], st);

    if (mode == 0) {
      #pragma unroll
      for (int j = 0; j < 4; ++j) {
        const int q = q0w + (lane >> 4) * 4 + j;
        if (q < SS) {
          const float inv = 1.0f / ps[j];
          float* op = out + (size_t)(b * SS + q) * AA + (lane & 15);
          #pragma unroll
          for (int n = 0; n < 32; ++n) op[n * 16] = o[n][j] * inv;
        }
      }
    } else {
      const int slot = mode - 1;
      #pragma unroll
      for (int j = 0; j < 4; ++j) {
        const int rl = wave * 16 + (lane >> 4) * 4 + j;
        const size_t idx = (size_t)slot * PROWS + ((size_t)(b * 3 + cidx) * 128 + rl);
        float* po = part + idx * 512 + (lane & 15);
        #pragma unroll
        for (int n = 0; n < 32; ++n) po[n * 16] = o[n][j];
        if ((lane & 15) == 0) {
          float* pml = part + ML_OFF + idx * 2;
          pml[0] = mrun[j];
          pml[1] = ps[j];
        }
      }
    }
  }
}

// ---------------------------------------------------------------- combine partials
__global__ __launch_bounds__(256) void combine_kernel(const float* __restrict__ part,
                                                      float* __restrict__ out) {
  const int rid = blockIdx.x * 2 + (threadIdx.x >> 7);
  const int t = threadIdx.x & 127;
  const int b = rid / 384;
  const int rem = rid - b * 384;
  const int c = rem >> 7, row = rem & 127;
  const int q = (c + 5) * 128 + row;
  if (q >= SS) return;
  const float* mlA = part + ML_OFF + (size_t)rid * 2;
  const float* mlB = part + ML_OFF + ((size_t)PROWS + rid) * 2;
  const float mA = mlA[0], lA = mlA[1];
  const float mB = mlB[0], lB = mlB[1];
  const float m = fmaxf(mA, mB);
  const float sA = fast_exp2(mA - m), sB = fast_exp2(mB - m);
  const float inv = 1.0f / (lA * sA + lB * sB);
  const float4 a = ((const float4*)(part + (size_t)rid * 512))[t];
  const float4 d = ((const float4*)(part + ((size_t)PROWS + rid) * 512))[t];
  float4 r;
  r.x = (a.x * sA + d.x * sB) * inv;
  r.y = (a.y * sA + d.y * sB) * inv;
  r.z = (a.z * sA + d.z * sB) * inv;
  r.w = (a.w * sA + d.w * sB) * inv;
  ((float4*)(out + ((size_t)b * SS + q) * AA))[t] = r;
}

// ---------------------------------------------------------------- launch
extern "C" void kernel_launch(void* const* d_in, const int* in_sizes, int n_in,
                              void* d_out, int out_size, void* d_ws, size_t ws_size,
                              hipStream_t stream) {
  const float* x  = (const float*)d_in[0];
  const float* Wk = (const float*)d_in[1];
  const float* bk = (const float*)d_in[2];
  const float* Wq = (const float*)d_in[3];
  const float* bq = (const float*)d_in[4];
  const float* Wv = (const float*)d_in[5];
  const float* bv = (const float*)d_in[6];

  char* ws = (char*)d_ws;
  unsigned short* X16 = (unsigned short*)(ws + OFF_X16);
  unsigned short* Qw  = (unsigned short*)(ws + OFF_Q);
  unsigned short* Kw  = (unsigned short*)(ws + OFF_K);
  unsigned short* VTw = (unsigned short*)(ws + OFF_VT);
  unsigned short* WT  = (unsigned short*)(ws + OFF_WT);
  float* Part = (float*)(ws + OFF_X16);

  x_to_bf16_kernel<<<dim3(2048), dim3(256), 0, stream>>>(x, X16);
  wt_kernel<<<dim3(EE / 64, AA / 64, 3), dim3(256), 0, stream>>>(Wq, Wk, Wv, WT);
  proj_kernel<<<dim3(750), dim3(512), 0, stream>>>(
      X16, WT, bq, bk, bv, Qw, Kw, VTw);
  attn_kernel<<<dim3(256), dim3(512), 0, stream>>>(Qw, Kw, VTw, (float*)d_out, Part);
  combine_kernel<<<dim3(PROWS / 2), dim3(256), 0, stream>>>(Part, (float*)d_out);
}

// Round 23
// 275.984 us; speedup vs baseline: 1.0041x; 1.0041x over previous
//
#include <hip/hip_runtime.h>
#include <hip/hip_bf16.h>
#include <stdint.h>

#define DEVI __device__ __forceinline__

typedef short s16x8 __attribute__((ext_vector_type(8)));
typedef short s16x4 __attribute__((ext_vector_type(4)));
typedef float f32x4 __attribute__((ext_vector_type(4)));

static constexpr int BB = 32, SS = 1000, EE = 1024, AA = 512;
static constexpr int MM = BB * SS;  // 32000

// workspace layout (bytes)
static constexpr size_t OFF_X16 = 0;                                   // [M][E] bf16 (dead after proj -> attn partials)
static constexpr size_t OFF_Q   = OFF_X16 + (size_t)MM * EE * 2;       // [M][A] bf16 (pre-scaled by log2e/sqrt(S))
static constexpr size_t OFF_K   = OFF_Q  + (size_t)MM * AA * 2;        // [M][A] bf16
static constexpr size_t OFF_VT  = OFF_K  + (size_t)MM * AA * 2;        // [B][A][S] bf16
static constexpr size_t OFF_WT  = OFF_VT + (size_t)BB * AA * SS * 2;   // 3 x [A][E] bf16

// attn K-split partials (inside dead X16 region): chunks 4..7 (rows 512..1023),
// 2 slots. O-partials stored BF16 (33.6MB), m/l pairs f32 after them.
static constexpr int PROWS = BB * 4 * 128;                         // 16384 rows/slot
static constexpr size_t PART_O_ELEMS = (size_t)2 * PROWS * 512;    // bf16 elems
static constexpr int KSPLIT_T = 18;                                // split k-tile
// Finite "minus infinity": rows with zero valid cols in a phase keep m=MNEG,
// l=0, o=0; exp2(x - MNEG) underflows to 0 in combine (no NaN, unlike -inf).
#define MNEG (-3.0e38f)

DEVI unsigned short f2bf(float f) {
  union { float f; unsigned int u; } c; c.f = f;
  unsigned int u = c.u + 0x7fffu + ((c.u >> 16) & 1u);
  return (unsigned short)(u >> 16);
}

DEVI float bf2f(unsigned short h) {
  union { unsigned int u; float f; } c; c.u = ((unsigned int)h) << 16;
  return c.f;
}

DEVI void gl_lds16(const void* g, void* l) {
  __builtin_amdgcn_global_load_lds(
      (const __attribute__((address_space(1))) unsigned int*)g,
      (__attribute__((address_space(3))) unsigned int*)l, 16, 0, 0);
}

DEVI void wg_barrier() {
  asm volatile("" ::: "memory");
  __builtin_amdgcn_s_barrier();
  asm volatile("" ::: "memory");
}

DEVI float fast_exp2(float x) {
#if __has_builtin(__builtin_amdgcn_exp2f)
  return __builtin_amdgcn_exp2f(x);
#else
  return __builtin_exp2f(x);
#endif
}

// ---------------------------------------------------------------- prep kernels
__global__ __launch_bounds__(256) void x_to_bf16_kernel(const float* __restrict__ x,
                                                        unsigned short* __restrict__ x16) {
  const long n4 = (long)MM * EE / 4;
  long i = (long)blockIdx.x * blockDim.x + threadIdx.x;
  const long stride = (long)gridDim.x * blockDim.x;
  for (; i < n4; i += stride) {
    const float4 v = ((const float4*)x)[i];
    ushort4 o;
    o.x = f2bf(v.x); o.y = f2bf(v.y); o.z = f2bf(v.z); o.w = f2bf(v.w);
    ((ushort4*)x16)[i] = o;
  }
}

__global__ __launch_bounds__(256) void wt_kernel(const float* __restrict__ Wq,
                                                 const float* __restrict__ Wk,
                                                 const float* __restrict__ Wv,
                                                 unsigned short* __restrict__ WT) {
  const float* W = (blockIdx.z == 0) ? Wq : (blockIdx.z == 1) ? Wk : Wv;
  unsigned short* out = WT + (size_t)blockIdx.z * AA * EE;
  __shared__ unsigned short t[64][65];
  const int k0 = blockIdx.x * 64, n0 = blockIdx.y * 64;
  #pragma unroll
  for (int i = 0; i < 16; ++i) {
    int idx = i * 256 + threadIdx.x;
    int r = idx >> 6, c = idx & 63;
    t[r][c] = f2bf(W[(size_t)(k0 + r) * AA + n0 + c]);
  }
  __syncthreads();
  #pragma unroll
  for (int i = 0; i < 16; ++i) {
    int idx = i * 256 + threadIdx.x;
    int r = idx >> 6, c = idx & 63;
    out[(size_t)(n0 + r) * EE + k0 + c] = t[c][r];
  }
}

// ---------------------------------------------------------------- QKV projection
// (unchanged R21 fat-phase: 256x256, BK=64, 8 waves, 4 fat phases/K-pair,
// XCD-panel-pinned grid 750)
#define PROJ_PHASE4(BUF, QA, SKT, SWHa, SWHb, SBUF, DOVM)                      \
  {                                                                            \
    if ((QA) == 0) {                                                           \
      _Pragma("unroll") for (int kk = 0; kk < 2; ++kk) {                       \
        _Pragma("unroll") for (int g2 = 0; g2 < 4; ++g2) {                     \
          int row = wn * 64 + g2 * 16 + (lane & 15);                           \
          int cb = (kk * 64 + (lane >> 4) * 16) ^ ((row & 7) << 4);            \
          bR[kk][g2] = *(const s16x8*)(lds + 65536 + (BUF) * 32768 + row * 128 + cb); \
        }                                                                      \
      }                                                                        \
    }                                                                          \
    _Pragma("unroll") for (int kk = 0; kk < 2; ++kk) {                         \
      _Pragma("unroll") for (int f = 0; f < 4; ++f) {                          \
        int row = wm * 128 + ((QA) * 4 + f) * 16 + (lane & 15);                \
        int cb = (kk * 64 + (lane >> 4) * 16) ^ ((row & 7) << 4);              \
        aR[kk][f] = *(const s16x8*)(lds + (BUF) * 32768 + row * 128 + cb);     \
      }                                                                        \
    }                                                                          \
    if ((SKT) >= 0) { stage_half(SBUF, SKT, SWHa); stage_half(SBUF, SKT, SWHb); } \
    wg_barrier();                                                              \
    __builtin_amdgcn_s_setprio(1);                                             \
    _Pragma("unroll") for (int kk = 0; kk < 2; ++kk) {                         \
      _Pragma("unroll") for (int f = 0; f < 4; ++f) {                          \
        _Pragma("unroll") for (int g2 = 0; g2 < 4; ++g2) {                     \
          acc[(QA) * 4 + f][g2] = __builtin_amdgcn_mfma_f32_16x16x32_bf16(     \
              aR[kk][f], bR[kk][g2], acc[(QA) * 4 + f][g2], 0, 0, 0);          \
        }                                                                      \
      }                                                                        \
    }                                                                          \
    __builtin_amdgcn_s_setprio(0);                                             \
    if (DOVM) asm volatile("s_waitcnt vmcnt(0)" ::: "memory");                 \
    wg_barrier();                                                              \
  }

__global__ __launch_bounds__(512, 2) void proj_kernel(
    const unsigned short* __restrict__ X16, const unsigned short* __restrict__ WT,
    const float* __restrict__ bq, const float* __restrict__ bk, const float* __restrict__ bv,
    unsigned short* __restrict__ Qo, unsigned short* __restrict__ Ko,
    unsigned short* __restrict__ VTo) {
  __shared__ unsigned char lds[131072];  // A: [2 buf][256 rows][128B] @0 | B @65536
  const int tid = threadIdx.x, lane = tid & 63, wave = tid >> 6;
  const int wm = wave >> 2, wn = wave & 3;

  const int phys = blockIdx.x;
  int p, r;
  if (phys < 720) { int g = phys / 48, w = phys % 48; p = g * 8 + (w & 7); r = w >> 3; }
  else            { int w = phys - 720; p = 120 + w % 5; r = w / 5; }
  const int z = r >> 1, nidx = r & 1;
  const int m0 = p * 256, n0 = nidx * 256;
  const unsigned short* Wz = WT + (size_t)z * AA * EE;

  f32x4 acc[8][4];
  #pragma unroll
  for (int i = 0; i < 8; ++i)
    #pragma unroll
    for (int j = 0; j < 4; ++j) acc[i][j] = f32x4{0.f, 0.f, 0.f, 0.f};

  unsigned int offH[2];
  #pragma unroll
  for (int i = 0; i < 2; ++i) {
    int c = i * 512 + tid;
    int rl = c >> 3, s = c & 7;
    int cb = (s * 16) ^ ((rl & 7) << 4);
    offH[i] = (unsigned)(rl * EE + (cb >> 1));
  }
  auto stage_half = [&](int buf, int kt, int which) {
    const int h = which & 1;
    const int isB = which >> 1;
    const unsigned short* srcb = isB ? (Wz + (size_t)(n0 + h * 128) * EE + kt * 64)
                                     : (X16 + (size_t)(m0 + h * 128) * EE + kt * 64);
    unsigned char* dstb = lds + (isB ? 65536 : 0) + buf * 32768 + h * 16384;
    #pragma unroll
    for (int i = 0; i < 2; ++i)
      gl_lds16(srcb + offH[i], dstb + (i * 512 + tid) * 16);
  };

  stage_half(0, 0, 0); stage_half(0, 0, 1); stage_half(0, 0, 2); stage_half(0, 0, 3);
  asm volatile("s_waitcnt vmcnt(0)" ::: "memory");
  wg_barrier();

  s16x8 aR[2][4];
  s16x8 bR[2][4];
  for (int J = 0; J < 8; ++J) {
    const int t1 = 2 * J + 1;
    const int t2 = (J < 7) ? (2 * J + 2) : -1;
    PROJ_PHASE4(0, 0, t1, 0, 1, 1, false)
    PROJ_PHASE4(0, 1, t1, 2, 3, 1, true)
    PROJ_PHASE4(1, 0, t2, 0, 1, 0, false)
    PROJ_PHASE4(1, 1, t2, 2, 3, 0, true)
  }

  const float* bias = (z == 0) ? bq : (z == 1) ? bk : bv;
  const float scale = (z == 0) ? 0.04562280215f : 1.0f;
  unsigned short* T = (unsigned short*)lds;
  float bv4[4];
  #pragma unroll
  for (int nf = 0; nf < 4; ++nf) bv4[nf] = bias[n0 + wn * 64 + nf * 16 + (lane & 15)];

  if (z != 2) {
    unsigned short* O = (z == 0) ? Qo : Ko;
    #pragma unroll
    for (int h = 0; h < 2; ++h) {
      if (wm == h) {
        #pragma unroll
        for (int mf = 0; mf < 8; ++mf)
          #pragma unroll
          for (int nf = 0; nf < 4; ++nf) {
            const int col = wn * 64 + nf * 16 + (lane & 15);
            #pragma unroll
            for (int j = 0; j < 4; ++j) {
              const int rr = mf * 16 + (lane >> 4) * 4 + j;
              T[rr * 264 + col] = f2bf((acc[mf][nf][j] + bv4[nf]) * scale);
            }
          }
      }
      wg_barrier();
      #pragma unroll
      for (int i = 0; i < 8; ++i) {
        int c2 = i * 512 + tid;
        int rr = c2 >> 5, ch = (c2 & 31) * 8;
        s16x8 chunk = *(const s16x8*)&T[rr * 264 + ch];
        *(s16x8*)&O[(size_t)(m0 + h * 128 + rr) * AA + n0 + ch] = chunk;
      }
      wg_barrier();
    }
  } else {
    #pragma unroll
    for (int h = 0; h < 2; ++h) {
      if ((wn >> 1) == h) {
        #pragma unroll
        for (int mf = 0; mf < 8; ++mf)
          #pragma unroll
          for (int nf = 0; nf < 4; ++nf) {
            const int al = (wn & 1) * 64 + nf * 16 + (lane & 15);
            #pragma unroll
            for (int j = 0; j < 4; ++j) {
              const int sl = wm * 128 + mf * 16 + (lane >> 4) * 4 + j;
              T[al * 264 + sl] = f2bf(acc[mf][nf][j] + bv4[nf]);
            }
          }
      }
      wg_barrier();
      #pragma unroll
      for (int i = 0; i < 8; ++i) {
        int c2 = i * 512 + tid;
        int rr = c2 >> 5, ch = (c2 & 31) * 8;
        s16x8 chunk = *(const s16x8*)&T[rr * 264 + ch];
        const int rowg0 = m0 + ch;
        const int bb2 = rowg0 / SS, ss2 = rowg0 - bb2 * SS;
        *(s16x8*)&VTo[(size_t)bb2 * AA * SS + (size_t)(n0 + h * 128 + rr) * SS + ss2] = chunk;
      }
      wg_barrier();
    }
  }
}

// ---------------------------------------------------------------- fused causal attention
// K-SPLIT T=18: all 8 blocks run exactly 18 compute iters.
// Phase1: chunk g, tiles [0, min(4(g+1),18)); g<=3 complete (final store),
// g>=4 partial -> slot A (chunk idx g-4). Phase2 (g<=3): partner r=7-g, its
// tail [18, 4(r+1)) -> slot B (chunk idx r-4). O-partials bf16, m/l f32.
// mrun inits to finite MNEG so rows with ZERO valid cols in a phase (donated
// chunk-4 rows 512..575 have no unmasked tail entries) yield m=MNEG,l=0,o=0
// instead of NaN (exp2(-inf - -inf)); combine's exp2(MNEG - m) flushes to 0.
__global__ __launch_bounds__(512, 2) void attn_kernel(
    const unsigned short* __restrict__ Qs, const unsigned short* __restrict__ Ks,
    const unsigned short* __restrict__ VT, float* __restrict__ out,
    unsigned short* __restrict__ partO, float* __restrict__ partML) {
  constexpr int KVB = 32;
  __shared__ unsigned char ldsK[2][KVB * AA * 2];
  __shared__ unsigned char ldsV[2][AA * KVB * 2];
  __shared__ unsigned char ldsP[8][16 * 80];

  const int tid = threadIdx.x, lane = tid & 63, wave = tid >> 6;
  const int L = blockIdx.x;
  const int b = L & 31;
  const int g = 7 - (L >> 5);

  const unsigned short* kbase = Ks + (size_t)b * SS * AA;
  const unsigned short* vbase = VT + (size_t)b * AA * SS;
  unsigned int koff[4], voff[4];
  #pragma unroll
  for (int i = 0; i < 4; ++i) {
    int c = i * 512 + tid;
    int r = c >> 6;
    int cb = ((c & 63) * 16) ^ ((r & 7) << 4);
    koff[i] = r * AA + (cb >> 1);
    int pair = c >> 3;
    int within = (c & 7) * 16;
    int half = within >> 6;
    int kb = (within & 63) ^ ((pair & 3) << 4);
    int a_ = pair * 2 + half;
    voff[i] = a_ * SS + (kb >> 1);
  }

  auto stageKV = [&](int buf, int t) {
    #pragma unroll
    for (int i = 0; i < 4; ++i)
      gl_lds16(kbase + koff[i] + (unsigned)(t * (KVB * AA)),
               &ldsK[buf][(i * 512 + tid) * 16]);
    #pragma unroll
    for (int i = 0; i < 4; ++i)
      gl_lds16(vbase + voff[i] + (unsigned)(t * KVB),
               &ldsV[buf][(i * 512 + tid) * 16]);
  };

  int ownN = 4 * (g + 1);
  int rb_[2], t0_[2], t1_[2], md_[2], cx_[2];
  int nph = 1;
  rb_[0] = 128 * g; t0_[0] = 0; t1_[0] = (ownN < KSPLIT_T) ? ownN : KSPLIT_T;
  md_[0] = (g <= 3) ? 0 : 1; cx_[0] = g - 4;
  if (g <= 3) {
    int r = 7 - g;
    rb_[1] = 128 * r; t0_[1] = KSPLIT_T; t1_[1] = 4 * (r + 1); md_[1] = 2; cx_[1] = r - 4;
    nph = 2;
  }

  for (int ph = 0; ph < nph; ++ph) {
    const int rowbase = rb_[ph], tbeg = t0_[ph], tend = t1_[ph];
    const int mode = md_[ph], cidx = cx_[ph];
    const int q0w = rowbase + wave * 16;

    s16x8 qf[16];
    {
      int qrow = q0w + (lane & 15);
      int qr = qrow < SS ? qrow : SS - 1;
      const unsigned short* qp = Qs + (size_t)(b * SS + qr) * AA + (lane >> 4) * 8;
      #pragma unroll
      for (int f = 0; f < 16; ++f) qf[f] = *(const s16x8*)(qp + f * 32);
    }

    f32x4 o[32];
    #pragma unroll
    for (int n = 0; n < 32; ++n) o[n] = f32x4{0.f, 0.f, 0.f, 0.f};
    float mrun[4], ps[4];
    #pragma unroll
    for (int j = 0; j < 4; ++j) { mrun[j] = MNEG; ps[j] = 0.f; }

    stageKV(0, tbeg);
    asm volatile("s_waitcnt vmcnt(0)" ::: "memory");
    wg_barrier();

    for (int t = tbeg; t < tend; ++t) {
      const int cur = (t - tbeg) & 1;
      const int k0 = t * KVB;
      if (t + 1 < tend) stageKV(cur ^ 1, t + 1);

      f32x4 p0a = {0.f, 0.f, 0.f, 0.f}, p0b = {0.f, 0.f, 0.f, 0.f};
      f32x4 p1a = {0.f, 0.f, 0.f, 0.f}, p1b = {0.f, 0.f, 0.f, 0.f};
      {
        const int r0 = lane & 15;
        const int sw = (r0 & 7) << 4;
        const int kb16 = (lane >> 4) * 16;
        const int rb0 = r0 << 10, rb1 = (r0 + 16) << 10;
        #pragma unroll
        for (int f = 0; f < 8; ++f) {
          const int offA = f * 64 + kb16;
          const int offB = (f + 8) * 64 + kb16;
          s16x8 k0A = *(const s16x8*)&ldsK[cur][rb0 + (offA ^ sw)];
          s16x8 k1A = *(const s16x8*)&ldsK[cur][rb1 + (offA ^ sw)];
          s16x8 k0B = *(const s16x8*)&ldsK[cur][rb0 + (offB ^ sw)];
          s16x8 k1B = *(const s16x8*)&ldsK[cur][rb1 + (offB ^ sw)];
          p0a = __builtin_amdgcn_mfma_f32_16x16x32_bf16(qf[f], k0A, p0a, 0, 0, 0);
          p1a = __builtin_amdgcn_mfma_f32_16x16x32_bf16(qf[f], k1A, p1a, 0, 0, 0);
          p0b = __builtin_amdgcn_mfma_f32_16x16x32_bf16(qf[f + 8], k0B, p0b, 0, 0, 0);
          p1b = __builtin_amdgcn_mfma_f32_16x16x32_bf16(qf[f + 8], k1B, p1b, 0, 0, 0);
        }
      }
      f32x4 p0 = p0a + p0b, p1 = p1a + p1b;

      const int kcol = k0 + (lane & 15);
      float lm[4];
      #pragma unroll
      for (int j = 0; j < 4; ++j) {
        const int q = q0w + (lane >> 4) * 4 + j;
        float s0 = p0[j], s1 = p1[j];
        if (kcol > q || kcol >= SS) s0 = MNEG;
        if (kcol + 16 > q || kcol + 16 >= SS) s1 = MNEG;
        p0[j] = s0; p1[j] = s1;
        lm[j] = fmaxf(s0, s1);
      }
      const int myneed = (lm[0] > mrun[0] + 8.f) | (lm[1] > mrun[1] + 8.f) |
                         (lm[2] > mrun[2] + 8.f) | (lm[3] > mrun[3] + 8.f);
      if (__any(myneed)) {
        float rm[4] = {lm[0], lm[1], lm[2], lm[3]};
        #pragma unroll
        for (int st = 1; st <= 8; st <<= 1)
          #pragma unroll
          for (int j = 0; j < 4; ++j) rm[j] = fmaxf(rm[j], __shfl_xor(rm[j], st));
        float corr[4];
        #pragma unroll
        for (int j = 0; j < 4; ++j) {
          const float mnew = fmaxf(mrun[j], rm[j]);
          corr[j] = fast_exp2(mrun[j] - mnew);   // exp2(MNEG - x) flushes to 0
          mrun[j] = mnew;
          ps[j] *= corr[j];
        }
        #pragma unroll
        for (int n = 0; n < 32; ++n)
          #pragma unroll
          for (int j = 0; j < 4; ++j) o[n][j] *= corr[j];
      }
      #pragma unroll
      for (int j = 0; j < 4; ++j) {
        const float e0 = fast_exp2(p0[j] - mrun[j]);  // masked: exp2(MNEG-m)=0
        const float e1 = fast_exp2(p1[j] - mrun[j]);
        ps[j] += e0 + e1;
        p0[j] = e0; p1[j] = e1;
      }

      {
        unsigned short* pb = (unsigned short*)&ldsP[wave][0];
        const int prow = (lane >> 4) * 4, pc = lane & 15;
        #pragma unroll
        for (int j = 0; j < 4; ++j) {
          pb[(prow + j) * 40 + pc]      = f2bf(p0[j]);
          pb[(prow + j) * 40 + pc + 16] = f2bf(p1[j]);
        }
      }
      s16x8 pa;
      {
        const unsigned char* pp = &ldsP[wave][(lane & 15) * 80 + (lane >> 4) * 16];
        s16x4 lo = *(const s16x4*)pp;
        s16x4 hi = *(const s16x4*)(pp + 8);
        pa = s16x8{lo[0], lo[1], lo[2], lo[3], hi[0], hi[1], hi[2], hi[3]};
      }

      #pragma unroll
      for (int n = 0; n < 32; ++n) {
        const int a_ = n * 16 + (lane & 15);
        const int pair = a_ >> 1;
        const int off = pair * 128 + (a_ & 1) * 64 + (((lane >> 4) * 16) ^ ((pair & 3) << 4));
        s16x8 vb = *(const s16x8*)&ldsV[cur][off];
        o[n] = __builtin_amdgcn_mfma_f32_16x16x32_bf16(pa, vb, o[n], 0, 0, 0);
      }

      asm volatile("s_waitcnt vmcnt(0)" ::: "memory");
      wg_barrier();
    }

    #pragma unroll
    for (int st = 1; st <= 8; st <<= 1)
      #pragma unroll
      for (int j = 0; j < 4; ++j) ps[j] += __shfl_xor(ps[j], st);

    if (mode == 0) {
      #pragma unroll
      for (int j = 0; j < 4; ++j) {
        const int q = q0w + (lane >> 4) * 4 + j;
        if (q < SS) {
          const float inv = 1.0f / ps[j];
          float* op = out + (size_t)(b * SS + q) * AA + (lane & 15);
          #pragma unroll
          for (int n = 0; n < 32; ++n) op[n * 16] = o[n][j] * inv;
        }
      }
    } else {
      const int slot = mode - 1;
      #pragma unroll
      for (int j = 0; j < 4; ++j) {
        const int rl = wave * 16 + (lane >> 4) * 4 + j;       // row within chunk
        const size_t idx = (size_t)slot * PROWS + ((size_t)(b * 4 + cidx) * 128 + rl);
        unsigned short* po = partO + idx * 512 + (lane & 15);
        #pragma unroll
        for (int n = 0; n < 32; ++n) po[n * 16] = f2bf(o[n][j]);  // raw, bf16
        if ((lane & 15) == 0) {
          float* pml = partML + idx * 2;
          pml[0] = mrun[j];
          pml[1] = ps[j];
        }
      }
    }
  }
}

// ---------------------------------------------------------------- combine partials
// rows 512..999 of each batch (chunks 4..7): merge slot A (k head) + slot B (tail).
__global__ __launch_bounds__(256) void combine_kernel(const unsigned short* __restrict__ partO,
                                                      const float* __restrict__ partML,
                                                      float* __restrict__ out) {
  const int rid = blockIdx.x * 2 + (threadIdx.x >> 7);   // 0..16383
  const int t = threadIdx.x & 127;                       // 4-col group
  const int b = rid >> 9;                                // /512
  const int rem = rid & 511;
  const int c = rem >> 7, row = rem & 127;
  const int q = (c + 4) * 128 + row;
  if (q >= SS) return;
  const float* mlA = partML + (size_t)rid * 2;
  const float* mlB = partML + ((size_t)PROWS + rid) * 2;
  const float mA = mlA[0], lA = mlA[1];
  const float mB = mlB[0], lB = mlB[1];
  const float m = fmaxf(mA, mB);
  const float sA = fast_exp2(mA - m), sB = fast_exp2(mB - m);  // empty: exp2(MNEG-m)=0
  const float inv = 1.0f / (lA * sA + lB * sB);
  const ushort4 ua = ((const ushort4*)(partO + (size_t)rid * 512))[t];
  const ushort4 ud = ((const ushort4*)(partO + ((size_t)PROWS + rid) * 512))[t];
  float4 r;
  r.x = (bf2f(ua.x) * sA + bf2f(ud.x) * sB) * inv;
  r.y = (bf2f(ua.y) * sA + bf2f(ud.y) * sB) * inv;
  r.z = (bf2f(ua.z) * sA + bf2f(ud.z) * sB) * inv;
  r.w = (bf2f(ua.w) * sA + bf2f(ud.w) * sB) * inv;
  ((float4*)(out + ((size_t)b * SS + q) * AA))[t] = r;
}

// ---------------------------------------------------------------- launch
extern "C" void kernel_launch(void* const* d_in, const int* in_sizes, int n_in,
                              void* d_out, int out_size, void* d_ws, size_t ws_size,
                              hipStream_t stream) {
  const float* x  = (const float*)d_in[0];
  const float* Wk = (const float*)d_in[1];
  const float* bk = (const float*)d_in[2];
  const float* Wq = (const float*)d_in[3];
  const float* bq = (const float*)d_in[4];
  const float* Wv = (const float*)d_in[5];
  const float* bv = (const float*)d_in[6];

  char* ws = (char*)d_ws;
  unsigned short* X16 = (unsigned short*)(ws + OFF_X16);
  unsigned short* Qw  = (unsigned short*)(ws + OFF_Q);
  unsigned short* Kw  = (unsigned short*)(ws + OFF_K);
  unsigned short* VTw = (unsigned short*)(ws + OFF_VT);
  unsigned short* WT  = (unsigned short*)(ws + OFF_WT);
  unsigned short* PartO = (unsigned short*)(ws + OFF_X16);            // 33.6MB bf16
  float* PartML = (float*)(ws + OFF_X16 + PART_O_ELEMS * 2);          // f32 m/l pairs

  x_to_bf16_kernel<<<dim3(2048), dim3(256), 0, stream>>>(x, X16);
  wt_kernel<<<dim3(EE / 64, AA / 64, 3), dim3(256), 0, stream>>>(Wq, Wk, Wv, WT);
  proj_kernel<<<dim3(750), dim3(512), 0, stream>>>(
      X16, WT, bq, bk, bv, Qw, Kw, VTw);
  attn_kernel<<<dim3(256), dim3(512), 0, stream>>>(Qw, Kw, VTw, (float*)d_out,
                                                   PartO, PartML);
  combine_kernel<<<dim3(PROWS / 2), dim3(256), 0, stream>>>(PartO, PartML, (float*)d_out);
}